// Round 16
// baseline (171.515 us; speedup 1.0000x reference)
//
#include <hip/hip_runtime.h>

typedef unsigned short u16;
typedef __attribute__((ext_vector_type(8))) short short8;
typedef __attribute__((ext_vector_type(4))) float f32x4;
typedef __attribute__((ext_vector_type(16))) float f32x16;

constexpr int BATCH = 8, CC = 128, CE = 256, DIM = 128, NTOK = 4096;
constexpr int KSPLIT = 4, KVB = 32, KTILES = NTOK / KSPLIT / KVB;   // 32 tiles
// 1/sqrt(128) * log2(e), folded into Wq/bq at conversion time
constexpr float KSC = 0.088388347648318447f * 1.4426950408889634f;

#define DEV static __device__ __forceinline__

DEV u16 f2bf(float f) {
    union { float f; unsigned u; } v; v.f = f;
    unsigned r = (v.u + 0x7fffu + ((v.u >> 16) & 1u)) >> 16;
    return (u16)r;
}
DEV float bf2f(u16 h) {
    union { unsigned u; float f; } v; v.u = ((unsigned)h) << 16;
    return v.f;
}
DEV short8 mk8(unsigned a, unsigned b, unsigned c, unsigned d) {
    union { unsigned u[4]; short8 s; } t; t.u[0] = a; t.u[1] = b; t.u[2] = c; t.u[3] = d;
    return t.s;
}

// ---------------------------------------------------------------------------
// Kernel 0a: transpose+convert inputs: [B][C][N] f32 -> [B][N][C] bf16.
// ---------------------------------------------------------------------------
__global__ __launch_bounds__(256)
void xpose_kernel(const float* __restrict__ cape, const float* __restrict__ era5,
                  u16* __restrict__ capeT, u16* __restrict__ era5T)
{
    __shared__ __align__(16) u16 sT[64 * 68];
    const int tid = threadIdx.x;
    const int nbase = blockIdx.x * 64;
    const int ct = blockIdx.y;
    const int b = blockIdx.z;

    const float* src; u16* dst; int pitch, c0;
    if (ct < 2) { src = cape + ((size_t)b * CC + ct * 64) * NTOK;
                  dst = capeT + (size_t)b * NTOK * CC; pitch = CC; c0 = ct * 64; }
    else        { src = era5 + ((size_t)b * CE + (ct - 2) * 64) * NTOK;
                  dst = era5T + (size_t)b * NTOK * CE; pitch = CE; c0 = (ct - 2) * 64; }

#pragma unroll
    for (int i = 0; i < 4; ++i) {
        int lin = tid + 256 * i;
        int c = lin >> 4, n4 = (lin & 15) * 4;
        float4 v = *(const float4*)&src[(size_t)c * NTOK + nbase + n4];
        ushort4 h; h.x = f2bf(v.x); h.y = f2bf(v.y); h.z = f2bf(v.z); h.w = f2bf(v.w);
        *(ushort4*)&sT[c * 68 + n4] = h;
    }
    __syncthreads();
#pragma unroll
    for (int i = 0; i < 2; ++i) {
        int lin = tid + 256 * i;
        int n = lin >> 3, cs = (lin & 7) * 8;
        short8 o;
#pragma unroll
        for (int j = 0; j < 8; ++j) o[j] = (short)sT[(cs + j) * 68 + n];
        *(short8*)&dst[(size_t)(nbase + n) * pitch + c0 + cs] = o;
    }
}

// ---------------------------------------------------------------------------
// Kernel 0b: convert Wq/Wk/Wv/Wo f32 -> bf16. Wq pre-scaled by KSC. grid 96.
// ---------------------------------------------------------------------------
__global__ __launch_bounds__(256)
void wconv_kernel(const float* __restrict__ Wq, const float* __restrict__ Wk,
                  const float* __restrict__ Wv, const float* __restrict__ Wo,
                  u16* __restrict__ Wqb, u16* __restrict__ Wkb,
                  u16* __restrict__ Wvb, u16* __restrict__ Wob)
{
    int lin = (blockIdx.x * 256 + threadIdx.x) * 4;
    const float* s; u16* d; int off; float sc;
    if (lin < 16384)      { s = Wq; d = Wqb; off = lin; sc = KSC; }
    else if (lin < 49152) { s = Wk; d = Wkb; off = lin - 16384; sc = 1.f; }
    else if (lin < 81920) { s = Wv; d = Wvb; off = lin - 49152; sc = 1.f; }
    else                  { s = Wo; d = Wob; off = lin - 81920; sc = 1.f; }
    float4 v = *(const float4*)&s[off];
    ushort4 h; h.x = f2bf(v.x * sc); h.y = f2bf(v.y * sc);
    h.z = f2bf(v.z * sc); h.w = f2bf(v.w * sc);
    *(ushort4*)&d[off] = h;
}

// ---------------------------------------------------------------------------
// Kernel 1: MFMA QKV projection (unchanged; bq scaled by KSC).
// ---------------------------------------------------------------------------
__global__ __launch_bounds__(256)
void qkv_proj_kernel(const u16* __restrict__ capeT, const u16* __restrict__ era5T,
                     const u16* __restrict__ Wqb, const u16* __restrict__ Wkb,
                     const u16* __restrict__ Wvb, const float* __restrict__ bq,
                     const float* __restrict__ bk, const float* __restrict__ bv,
                     u16* __restrict__ Qb, u16* __restrict__ Kb, u16* __restrict__ Vb)
{
    __shared__ __align__(16) u16 sT[4][32 * 68];

    const int tid = threadIdx.x, lane = tid & 63, w = tid >> 6;
    const int l31 = lane & 31, half = lane >> 5;
    const int b = blockIdx.y, nbase = blockIdx.x * 64;
    const int d = w * 32 + l31;

    f32x16 aq0, aq1;
#pragma unroll
    for (int r = 0; r < 16; ++r) { aq0[r] = 0.f; aq1[r] = 0.f; }
    {
        const u16* xr0 = capeT + ((size_t)b * NTOK + nbase + l31) * CC + half * 8;
        const u16* xr1 = xr0 + 32 * CC;
        const u16* wr  = Wqb + (size_t)d * CC + half * 8;
#pragma unroll
        for (int kc = 0; kc < 8; ++kc) {
            short8 a0 = *(const short8*)(xr0 + kc * 16);
            short8 a1 = *(const short8*)(xr1 + kc * 16);
            short8 bw = *(const short8*)(wr + kc * 16);
            aq0 = __builtin_amdgcn_mfma_f32_32x32x16_bf16(a0, bw, aq0, 0, 0, 0);
            aq1 = __builtin_amdgcn_mfma_f32_32x32x16_bf16(a1, bw, aq1, 0, 0, 0);
        }
    }
    {
        const float bias = bq[d] * KSC;
        u16* q0 = Qb + ((size_t)b * NTOK + nbase) * DIM + d;
#pragma unroll
        for (int r = 0; r < 16; ++r) {
            const int nl = (r & 3) + 8 * (r >> 2) + 4 * half;
            q0[(size_t)nl * DIM] = f2bf(aq0[r] + bias);
            q0[(size_t)(nl + 32) * DIM] = f2bf(aq1[r] + bias);
        }
    }

    f32x16 ak0, ak1, av0, av1;
#pragma unroll
    for (int r = 0; r < 16; ++r) { ak0[r] = 0.f; ak1[r] = 0.f; av0[r] = 0.f; av1[r] = 0.f; }
    {
        const u16* er0 = era5T + ((size_t)b * NTOK + nbase + l31) * CE + half * 8;
        const u16* er1 = er0 + 32 * CE;
        const u16* wkr = Wkb + (size_t)d * CE + half * 8;
        const u16* wvr = Wvb + (size_t)d * CE + half * 8;
#pragma unroll
        for (int kc = 0; kc < 16; ++kc) {
            short8 a0 = *(const short8*)(er0 + kc * 16);
            short8 a1 = *(const short8*)(er1 + kc * 16);
            short8 bwk = *(const short8*)(wkr + kc * 16);
            short8 bwv = *(const short8*)(wvr + kc * 16);
            ak0 = __builtin_amdgcn_mfma_f32_32x32x16_bf16(a0, bwk, ak0, 0, 0, 0);
            ak1 = __builtin_amdgcn_mfma_f32_32x32x16_bf16(a1, bwk, ak1, 0, 0, 0);
            av0 = __builtin_amdgcn_mfma_f32_32x32x16_bf16(a0, bwv, av0, 0, 0, 0);
            av1 = __builtin_amdgcn_mfma_f32_32x32x16_bf16(a1, bwv, av1, 0, 0, 0);
        }
    }
    {
        const float bias = bk[d];
        u16* k0 = Kb + ((size_t)b * NTOK + nbase) * DIM + d;
#pragma unroll
        for (int r = 0; r < 16; ++r) {
            const int nl = (r & 3) + 8 * (r >> 2) + 4 * half;
            k0[(size_t)nl * DIM] = f2bf(ak0[r] + bias);
            k0[(size_t)(nl + 32) * DIM] = f2bf(ak1[r] + bias);
        }
    }
    {
        const float bias = bv[d];
        u16* t = &sT[w][0];
#pragma unroll
        for (int r = 0; r < 16; ++r) {
            const int nl = (r & 3) + 8 * (r >> 2) + 4 * half;
            t[l31 * 68 + nl] = f2bf(av0[r] + bias);
            t[l31 * 68 + nl + 32] = f2bf(av1[r] + bias);
        }
#pragma unroll
        for (int i = 0; i < 4; ++i) {
            int rlin = lane + 64 * i;
            int dl = rlin >> 3, n8 = (rlin & 7) * 8;
            uint2 p0 = *(const uint2*)&t[dl * 68 + n8];
            uint2 p1 = *(const uint2*)&t[dl * 68 + n8 + 4];
            uint4 o = {p0.x, p0.y, p1.x, p1.y};
            *(uint4*)&Vb[((size_t)b * DIM + w * 32 + dl) * NTOK + nbase + n8] = o;
        }
    }
}

// ---------------------------------------------------------------------------
// Kernel 2: flash attention. Round-13 T15 schedule (proven), KVB=32 tile
// math (round-7 fragments, proven), KSPLIT=4 -> grid 1024, 32KB LDS ->
// 4 blocks/CU target (16 waves/CU). ks-outer decode: one K/V quarter (2MB)
// per XCD's resident set. KTILES=32 (barrier count/block unchanged).
// ---------------------------------------------------------------------------
__global__ __launch_bounds__(256, 3)
void attn_kernel(const u16* __restrict__ Qb, const u16* __restrict__ Kb,
                 const u16* __restrict__ Vb, u16* __restrict__ Op,
                 float* __restrict__ Lp)
{
    __shared__ __align__(16) u16 sK[2][KVB * 128];   // [buf][ktok][d], chunk c^(ktok&7)
    __shared__ __align__(16) u16 sV[2][128 * KVB];   // [buf][d][ktok], chunk c^(d&3)

    const int tid = threadIdx.x;
    const int lane = tid & 63, w = tid >> 6;        // 4 waves
    const int l31 = lane & 31, half = lane >> 5;

    // XCD-aware decode: b = lin&7 == XCD id; ks OUTER so resident blocks on
    // an XCD share one K/V quarter (2MB < 4MB L2).
    const int lin = blockIdx.x;
    const int b = lin & 7;
    const int rem = lin >> 3;               // 0..127
    const int qt = rem & 31;
    const int ks = rem >> 5;                // 0..3
    const int qbase = qt * 128 + w * 32;
    const int kbase = ks * (NTOK / KSPLIT);

    const u16* Kbat = Kb + (size_t)b * NTOK * DIM;
    const u16* Vbat = Vb + (size_t)b * DIM * NTOK;

    // 4 global_load_lds per wave per tile: 2 K-groups + 2 V-groups (unified)
#define STAGE(bufK, bufV, tt)                                                          \
    {                                                                                  \
        const u16* kb0 = Kbat + (size_t)(kbase + (tt) * KVB) * DIM;                    \
        _Pragma("unroll")                                                              \
        for (int i = 0; i < 2; ++i) {                                                  \
            const int row = w * 8 + i * 4 + (lane >> 4);                               \
            const int p = lane & 15;                                                   \
            const u16* g = kb0 + (size_t)row * DIM + ((p ^ (row & 7)) * 8);            \
            __builtin_amdgcn_global_load_lds(                                          \
                (const __attribute__((address_space(1))) unsigned int*)g,              \
                (__attribute__((address_space(3))) unsigned int*)&(bufK)[(w * 8 + i * 4) * 128], \
                16, 0, 0);                                                             \
        }                                                                              \
        const u16* vb0 = Vbat + kbase + (tt) * KVB;                                    \
        _Pragma("unroll")                                                              \
        for (int i = 0; i < 2; ++i) {                                                  \
            const int row = w * 32 + i * 16 + (lane >> 2);                             \
            const int p = lane & 3;                                                    \
            const u16* g = vb0 + (size_t)row * NTOK + ((p ^ (row & 3)) * 8);           \
            __builtin_amdgcn_global_load_lds(                                          \
                (const __attribute__((address_space(1))) unsigned int*)g,              \
                (__attribute__((address_space(3))) unsigned int*)&(bufV)[(w * 32 + i * 16) * KVB], \
                16, 0, 0);                                                             \
        }                                                                              \
    }

    // Q fragments first (oldest vm-ops; counted prologue wait stays safe)
    short8 aQ[8];
    {
        const u16* qrow = Qb + ((size_t)b * NTOK + qbase + l31) * DIM + half * 8;
#pragma unroll
        for (int s = 0; s < 8; ++s) aQ[s] = *(const short8*)&qrow[s * 16];
    }

    STAGE(sK[0], sV[0], 0);
    STAGE(sK[1], sV[1], 1);

    f32x16 O[4];
#pragma unroll
    for (int i = 0; i < 4; ++i)
#pragma unroll
        for (int r = 0; r < 16; ++r) O[i][r] = 0.f;
    f32x16 SA, SB;
#pragma unroll
    for (int r = 0; r < 16; ++r) SA[r] = 0.f;
    float lA = 0.f;

    // prologue: QK^T(0) into SA (drain STAGE(0); STAGE(1) stays in flight)
    asm volatile("s_waitcnt vmcnt(4)" ::: "memory");
    __builtin_amdgcn_s_barrier();
    __builtin_amdgcn_sched_barrier(0);
    __builtin_amdgcn_s_setprio(1);
#pragma unroll
    for (int s = 0; s < 8; ++s) {
        const int pos = (((s * 2 + half) ^ (l31 & 7)) * 8);
        short8 k0 = *(const short8*)&sK[0][l31 * 128 + pos];
        SA = __builtin_amdgcn_mfma_f32_32x32x16_bf16(k0, aQ[s], SA, 0, 0, 0);
    }
    __builtin_amdgcn_s_setprio(0);

    // softmax one k-group: 4 exp2 + lane-local l adds + 2 packed cvt
#define SM_ONE(s, SC)                                                                 \
    {                                                                                 \
        float p0 = __builtin_amdgcn_exp2f((SC)[(s) * 4 + 0]);                         \
        float p1 = __builtin_amdgcn_exp2f((SC)[(s) * 4 + 1]);                         \
        float p2 = __builtin_amdgcn_exp2f((SC)[(s) * 4 + 2]);                         \
        float p3 = __builtin_amdgcn_exp2f((SC)[(s) * 4 + 3]);                         \
        lA += (p0 + p1) + (p2 + p3);                                                  \
        asm("v_cvt_pk_bf16_f32 %0, %1, %2" : "=v"(xm[s]) : "v"(p0), "v"(p1));         \
        asm("v_cvt_pk_bf16_f32 %0, %1, %2" : "=v"(ym[s]) : "v"(p2), "v"(p3));         \
    }

    // one pipeline stage: softmax(SC(t)) interleaved with QK^T(t+1 -> SN), PV(t)
#define BODY(t, SC, SN)                                                               \
    {                                                                                 \
        const bool hasNext = ((t) + 1 < KTILES);                                      \
        if (hasNext) {                                                                \
            asm volatile("s_waitcnt vmcnt(0)" ::: "memory");                          \
            __builtin_amdgcn_s_barrier();                                             \
            __builtin_amdgcn_sched_barrier(0);                                        \
        }                                                                             \
        const u16* sKn = &sK[((t) + 1) & 1][0];                                       \
        const u16* sVc = &sV[(t) & 1][0];                                             \
        unsigned xm[4], ym[4];                                                        \
        if (hasNext) {                                                                \
            _Pragma("unroll")                                                         \
            for (int r = 0; r < 16; ++r) (SN)[r] = 0.f;                               \
            __builtin_amdgcn_s_setprio(1);                                            \
            _Pragma("unroll")                                                         \
            for (int s = 0; s < 8; ++s) {                                             \
                const int pos = (((s * 2 + half) ^ (l31 & 7)) * 8);                   \
                short8 k0 = *(const short8*)&sKn[l31 * 128 + pos];                    \
                (SN) = __builtin_amdgcn_mfma_f32_32x32x16_bf16(k0, aQ[s], (SN), 0, 0, 0); \
                if ((s) < 4) SM_ONE(s, SC)                                            \
            }                                                                         \
            __builtin_amdgcn_s_setprio(0);                                            \
        } else {                                                                      \
            _Pragma("unroll")                                                         \
            for (int s = 0; s < 4; ++s) SM_ONE(s, SC)                                 \
        }                                                                             \
        short8 pa[2];                                                                 \
        _Pragma("unroll")                                                             \
        for (int s2 = 0; s2 < 2; ++s2) {                                              \
            unsigned xa = xm[2 * s2], xb = xm[2 * s2 + 1];                            \
            unsigned ya = ym[2 * s2], yb = ym[2 * s2 + 1];                            \
            asm("v_permlane32_swap_b32 %0, %1" : "+v"(xa), "+v"(xb));                 \
            asm("v_permlane32_swap_b32 %0, %1" : "+v"(ya), "+v"(yb));                 \
            pa[s2] = mk8(xa, ya, xb, yb);                                             \
        }                                                                             \
        __builtin_amdgcn_s_setprio(1);                                                \
        _Pragma("unroll")                                                             \
        for (int dblk = 0; dblk < 4; ++dblk) {                                        \
            const int vrow = dblk * 32 + l31;                                         \
            _Pragma("unroll")                                                         \
            for (int s2 = 0; s2 < 2; ++s2) {                                          \
                short8 v = *(const short8*)&sVc[vrow * KVB + (((s2 * 2 + half) ^ (vrow & 3)) * 8)]; \
                O[dblk] = __builtin_amdgcn_mfma_f32_32x32x16_bf16(pa[s2], v, O[dblk], 0, 0, 0); \
            }                                                                         \
        }                                                                             \
        __builtin_amdgcn_s_setprio(0);                                                \
        __builtin_amdgcn_sched_barrier(0);                                            \
        __builtin_amdgcn_s_barrier();                                                 \
        __builtin_amdgcn_sched_barrier(0);                                            \
        if ((t) + 2 < KTILES) STAGE(sK[(t) & 1], sV[(t) & 1], (t) + 2);               \
    }

#pragma unroll 1
    for (int tp = 0; tp < KTILES; tp += 2) {
        BODY(tp,     SA, SB)
        BODY(tp + 1, SB, SA)
    }
#undef BODY
#undef SM_ONE
#undef STAGE

    // ---- epilogue: store UNNORMALIZED partials
    float lt = lA + __shfl_xor(lA, 32, 64);
    if (half == 0) {
        float* lp = Lp + (size_t)(ks * BATCH + b) * NTOK + qbase;
        lp[l31] = lt;
    }

    u16* obase = Op + ((size_t)(ks * BATCH + b) * NTOK + qbase) * DIM;
#pragma unroll
    for (int dblk = 0; dblk < 4; ++dblk)
#pragma unroll
        for (int r = 0; r < 16; ++r) {
            const int q = (r & 3) + 8 * (r >> 2) + 4 * half;
            obase[(size_t)q * DIM + dblk * 32 + l31] = f2bf(O[dblk][r]);
        }
}

// ---------------------------------------------------------------------------
// Kernel 3: combine KSPLIT=4 partials + MFMA output projection.
// ---------------------------------------------------------------------------
__global__ __launch_bounds__(256)
void oproj_kernel(const u16* __restrict__ Op, const float* __restrict__ Lp,
                  const u16* __restrict__ Wob, const float* __restrict__ bo,
                  float* __restrict__ Out)
{
    __shared__ __align__(16) u16 sA[64 * 128];   // [n][d], 16B chunk at c^(n&7)

    const int tid = threadIdx.x, lane = tid & 63, w = tid >> 6;
    const int l31 = lane & 31, half = lane >> 5;
    const int b = blockIdx.y;
    const int nbase = blockIdx.x * 64;

    // ---- combine split-K partials, normalize, stage bf16 to swizzled LDS
#pragma unroll
    for (int i = 0; i < 4; ++i) {
        int idx = tid + 256 * i;
        int c = idx & 15, n = idx >> 4;
        float acc[8];
#pragma unroll
        for (int j = 0; j < 8; ++j) acc[j] = 0.f;
        float l = 0.f;
#pragma unroll
        for (int ks = 0; ks < KSPLIT; ++ks) {
            const size_t rr = ((size_t)(ks * BATCH + b) * NTOK + nbase + n) * DIM + c * 8;
            uint4 v = *(const uint4*)&Op[rr];
            unsigned tt[4] = {v.x, v.y, v.z, v.w};
#pragma unroll
            for (int j = 0; j < 8; ++j)
                acc[j] += bf2f((u16)(tt[j >> 1] >> ((j & 1) * 16)));
            l += Lp[(size_t)(ks * BATCH + b) * NTOK + nbase + n];
        }
        float inv = 1.f / l;
        short8 o;
#pragma unroll
        for (int j = 0; j < 8; ++j) o[j] = (short)f2bf(acc[j] * inv);
        *(short8*)&sA[n * 128 + ((c ^ (n & 7)) * 8)] = o;
    }
    __syncthreads();

    // ---- MFMA: acc[nsub] += A(sA rows) x B(Wo rows)
    const int co = w * 32 + l31;
    const u16* wr = Wob + (size_t)co * DIM + half * 8;
    f32x16 acc0, acc1;
#pragma unroll
    for (int r = 0; r < 16; ++r) { acc0[r] = 0.f; acc1[r] = 0.f; }
#pragma unroll
    for (int kc = 0; kc < 8; ++kc) {
        const int ch = kc * 2 + half;
        short8 a0 = *(const short8*)&sA[l31 * 128 + ((ch ^ (l31 & 7)) * 8)];
        short8 a1 = *(const short8*)&sA[(32 + l31) * 128 + ((ch ^ (l31 & 7)) * 8)];
        short8 bw = *(const short8*)(wr + kc * 16);
        acc0 = __builtin_amdgcn_mfma_f32_32x32x16_bf16(a0, bw, acc0, 0, 0, 0);
        acc1 = __builtin_amdgcn_mfma_f32_32x32x16_bf16(a1, bw, acc1, 0, 0, 0);
    }

    // ---- epilogue: Out[b][co][nbase + n] = acc + bo[co]
    const float bb = bo[co];
    float* ob = Out + ((size_t)b * DIM + co) * NTOK + nbase;
#pragma unroll
    for (int r = 0; r < 16; ++r) {
        const int n = (r & 3) + 8 * (r >> 2) + 4 * half;
        ob[n] = acc0[r] + bb;
        ob[n + 32] = acc1[r] + bb;
    }
}

// ---------------------------------------------------------------------------
extern "C" void kernel_launch(void* const* d_in, const int* in_sizes, int n_in,
                              void* d_out, int out_size, void* d_ws, size_t ws_size,
                              hipStream_t stream)
{
    const float* cape = (const float*)d_in[0];
    const float* era5 = (const float*)d_in[1];
    const float* Wq = (const float*)d_in[2];
    const float* bq = (const float*)d_in[3];
    const float* Wk = (const float*)d_in[4];
    const float* bk = (const float*)d_in[5];
    const float* Wv = (const float*)d_in[6];
    const float* bv = (const float*)d_in[7];
    const float* Wo = (const float*)d_in[8];
    const float* bo = (const float*)d_in[9];

    const size_t QKV = (size_t)BATCH * NTOK * DIM;
    u16* Qb  = (u16*)d_ws;
    u16* Kb  = Qb + QKV;
    u16* Vb  = Kb + QKV;
    u16* Wqb = Vb + QKV;
    u16* Wkb = Wqb + 16384;
    u16* Wvb = Wkb + 32768;
    u16* Wob = Wvb + 32768;
    u16* regionA = Wob + 16384;
    // overlay 1 (lifetime: xpose..qkv_proj)
    u16* capeT = regionA;
    u16* era5T = capeT + QKV;
    // overlay 2 (lifetime: attn..oproj)
    u16* Op = regionA;
    float* Lp = (float*)(Op + (size_t)KSPLIT * QKV);

    hipLaunchKernelGGL(xpose_kernel, dim3(64, 6, BATCH), dim3(256), 0, stream,
                       cape, era5, capeT, era5T);
    hipLaunchKernelGGL(wconv_kernel, dim3(96), dim3(256), 0, stream,
                       Wq, Wk, Wv, Wo, Wqb, Wkb, Wvb, Wob);
    hipLaunchKernelGGL(qkv_proj_kernel, dim3(64, BATCH), dim3(256), 0, stream,
                       capeT, era5T, Wqb, Wkb, Wvb, bq, bk, bv, Qb, Kb, Vb);
    hipLaunchKernelGGL(attn_kernel, dim3((NTOK / 128) * KSPLIT * BATCH), dim3(256), 0, stream,
                       Qb, Kb, Vb, Op, Lp);
    hipLaunchKernelGGL(oproj_kernel, dim3(64, BATCH), dim3(256), 0, stream,
                       Op, Lp, Wob, bo, (float*)d_out);
}

// Round 17
// 108.422 us; speedup vs baseline: 1.5819x; 1.5819x over previous
//
#include <hip/hip_runtime.h>

typedef unsigned short u16;
typedef __attribute__((ext_vector_type(8))) short short8;
typedef __attribute__((ext_vector_type(4))) float f32x4;
typedef __attribute__((ext_vector_type(16))) float f32x16;

constexpr int BATCH = 8, CC = 128, CE = 256, DIM = 128, NTOK = 4096;
constexpr int KSPLIT = 2, KVB = 64, KTILES = NTOK / KSPLIT / KVB;   // 32 tiles
// 1/sqrt(128) * log2(e), folded into Wq/bq at conversion time
constexpr float KSC = 0.088388347648318447f * 1.4426950408889634f;

#define DEV static __device__ __forceinline__

DEV u16 f2bf(float f) {
    union { float f; unsigned u; } v; v.f = f;
    unsigned r = (v.u + 0x7fffu + ((v.u >> 16) & 1u)) >> 16;
    return (u16)r;
}
DEV float bf2f(u16 h) {
    union { unsigned u; float f; } v; v.u = ((unsigned)h) << 16;
    return v.f;
}
DEV short8 mk8(unsigned a, unsigned b, unsigned c, unsigned d) {
    union { unsigned u[4]; short8 s; } t; t.u[0] = a; t.u[1] = b; t.u[2] = c; t.u[3] = d;
    return t.s;
}

// ---------------------------------------------------------------------------
// Kernel 0: convert Wq/Wk/Wv/Wo f32 -> bf16. Wq pre-scaled by KSC. grid 96.
// ---------------------------------------------------------------------------
__global__ __launch_bounds__(256)
void wconv_kernel(const float* __restrict__ Wq, const float* __restrict__ Wk,
                  const float* __restrict__ Wv, const float* __restrict__ Wo,
                  u16* __restrict__ Wqb, u16* __restrict__ Wkb,
                  u16* __restrict__ Wvb, u16* __restrict__ Wob)
{
    int lin = (blockIdx.x * 256 + threadIdx.x) * 4;
    const float* s; u16* d; int off; float sc;
    if (lin < 16384)      { s = Wq; d = Wqb; off = lin; sc = KSC; }
    else if (lin < 49152) { s = Wk; d = Wkb; off = lin - 16384; sc = 1.f; }
    else if (lin < 81920) { s = Wv; d = Wvb; off = lin - 49152; sc = 1.f; }
    else                  { s = Wo; d = Wob; off = lin - 81920; sc = 1.f; }
    float4 v = *(const float4*)&s[off];
    ushort4 h; h.x = f2bf(v.x * sc); h.y = f2bf(v.y * sc);
    h.z = f2bf(v.z * sc); h.w = f2bf(v.w * sc);
    *(ushort4*)&d[off] = h;
}

// ---------------------------------------------------------------------------
// Kernel 1: FUSED transpose + MFMA QKV projection.
// Per block (nbase, b): stage 64c x 64n f32 chunks of cape/era5 into
// pitch-68 LDS (xpose's proven pattern), gather A-frags directly into
// registers (xpose's proven gather), MFMA against bf16 weights from L2.
// Eliminates the capeT/era5T HBM round-trip entirely.
// ---------------------------------------------------------------------------
__global__ __launch_bounds__(256)
void qkv_fused_kernel(const float* __restrict__ cape, const float* __restrict__ era5,
                      const u16* __restrict__ Wqb, const u16* __restrict__ Wkb,
                      const u16* __restrict__ Wvb, const float* __restrict__ bq,
                      const float* __restrict__ bk, const float* __restrict__ bv,
                      u16* __restrict__ Qb, u16* __restrict__ Kb, u16* __restrict__ Vb)
{
    __shared__ __align__(16) u16 sX[64 * 68];      // [c 64][n 64] pitch 68
    __shared__ __align__(16) u16 sT[4][32 * 68];   // per-wave V transpose tile

    const int tid = threadIdx.x, lane = tid & 63, w = tid >> 6;
    const int l31 = lane & 31, half = lane >> 5;
    const int b = blockIdx.y, nbase = blockIdx.x * 64;
    const int d = w * 32 + l31;

    // stage one 64c x 64n chunk (f32 -> bf16, pitch-68 LDS), coalesced rows
#define STAGE_X(srcbase)                                                      \
    {                                                                         \
        _Pragma("unroll")                                                     \
        for (int i = 0; i < 4; ++i) {                                         \
            int lin = tid + 256 * i;                                          \
            int c = lin >> 4, n4 = (lin & 15) * 4;                            \
            float4 v = *(const float4*)&(srcbase)[(size_t)c * NTOK + n4];     \
            ushort4 h; h.x = f2bf(v.x); h.y = f2bf(v.y);                      \
            h.z = f2bf(v.z); h.w = f2bf(v.w);                                 \
            *(ushort4*)&sX[c * 68 + n4] = h;                                  \
        }                                                                     \
    }
    // gather A-frags (rows l31 and 32+l31; c = kcl*16 + half*8 + j)
#define GATHER(kcl, a0, a1)                                                   \
    {                                                                         \
        _Pragma("unroll")                                                     \
        for (int j = 0; j < 8; ++j) {                                         \
            int c = (kcl) * 16 + half * 8 + j;                                \
            (a0)[j] = (short)sX[c * 68 + l31];                                \
            (a1)[j] = (short)sX[c * 68 + 32 + l31];                           \
        }                                                                     \
    }

    // ---- Q: cape, 2 chunks of 64 c
    f32x16 aq0, aq1;
#pragma unroll
    for (int r = 0; r < 16; ++r) { aq0[r] = 0.f; aq1[r] = 0.f; }
    {
        const u16* wq = Wqb + (size_t)d * CC + half * 8;
#pragma unroll 1
        for (int q = 0; q < 2; ++q) {
            if (q) __syncthreads();
            STAGE_X(cape + ((size_t)b * CC + q * 64) * NTOK + nbase);
            __syncthreads();
#pragma unroll
            for (int kcl = 0; kcl < 4; ++kcl) {
                short8 a0, a1;
                GATHER(kcl, a0, a1);
                short8 bw = *(const short8*)(wq + (q * 4 + kcl) * 16);
                aq0 = __builtin_amdgcn_mfma_f32_32x32x16_bf16(a0, bw, aq0, 0, 0, 0);
                aq1 = __builtin_amdgcn_mfma_f32_32x32x16_bf16(a1, bw, aq1, 0, 0, 0);
            }
        }
    }
    {
        const float bias = bq[d] * KSC;
        u16* q0 = Qb + ((size_t)b * NTOK + nbase) * DIM + d;
#pragma unroll
        for (int r = 0; r < 16; ++r) {
            const int nl = (r & 3) + 8 * (r >> 2) + 4 * half;
            q0[(size_t)nl * DIM] = f2bf(aq0[r] + bias);
            q0[(size_t)(nl + 32) * DIM] = f2bf(aq1[r] + bias);
        }
    }

    // ---- K & V: era5, 4 chunks of 64 c, shared A-frags
    f32x16 ak0, ak1, av0, av1;
#pragma unroll
    for (int r = 0; r < 16; ++r) { ak0[r] = 0.f; ak1[r] = 0.f; av0[r] = 0.f; av1[r] = 0.f; }
    {
        const u16* wk = Wkb + (size_t)d * CE + half * 8;
        const u16* wv = Wvb + (size_t)d * CE + half * 8;
#pragma unroll 1
        for (int e = 0; e < 4; ++e) {
            __syncthreads();
            STAGE_X(era5 + ((size_t)b * CE + e * 64) * NTOK + nbase);
            __syncthreads();
#pragma unroll
            for (int kcl = 0; kcl < 4; ++kcl) {
                short8 a0, a1;
                GATHER(kcl, a0, a1);
                short8 bwk = *(const short8*)(wk + (e * 4 + kcl) * 16);
                short8 bwv = *(const short8*)(wv + (e * 4 + kcl) * 16);
                ak0 = __builtin_amdgcn_mfma_f32_32x32x16_bf16(a0, bwk, ak0, 0, 0, 0);
                ak1 = __builtin_amdgcn_mfma_f32_32x32x16_bf16(a1, bwk, ak1, 0, 0, 0);
                av0 = __builtin_amdgcn_mfma_f32_32x32x16_bf16(a0, bwv, av0, 0, 0, 0);
                av1 = __builtin_amdgcn_mfma_f32_32x32x16_bf16(a1, bwv, av1, 0, 0, 0);
            }
        }
    }
    {
        const float bias = bk[d];
        u16* k0 = Kb + ((size_t)b * NTOK + nbase) * DIM + d;
#pragma unroll
        for (int r = 0; r < 16; ++r) {
            const int nl = (r & 3) + 8 * (r >> 2) + 4 * half;
            k0[(size_t)nl * DIM] = f2bf(ak0[r] + bias);
            k0[(size_t)(nl + 32) * DIM] = f2bf(ak1[r] + bias);
        }
    }
    // V: frag rows = n, cols = d -> transpose via per-wave LDS (pitch 68)
    {
        const float bias = bv[d];
        u16* t = &sT[w][0];
#pragma unroll
        for (int r = 0; r < 16; ++r) {
            const int nl = (r & 3) + 8 * (r >> 2) + 4 * half;
            t[l31 * 68 + nl] = f2bf(av0[r] + bias);
            t[l31 * 68 + nl + 32] = f2bf(av1[r] + bias);
        }
#pragma unroll
        for (int i = 0; i < 4; ++i) {
            int rlin = lane + 64 * i;
            int dl = rlin >> 3, n8 = (rlin & 7) * 8;
            uint2 p0 = *(const uint2*)&t[dl * 68 + n8];
            uint2 p1 = *(const uint2*)&t[dl * 68 + n8 + 4];
            uint4 o = {p0.x, p0.y, p1.x, p1.y};
            *(uint4*)&Vb[((size_t)b * DIM + w * 32 + dl) * NTOK + nbase + n8] = o;
        }
    }
#undef STAGE_X
#undef GATHER
}

// ---------------------------------------------------------------------------
// Kernel 2: flash attention — EXACT round-13 kernel (proven 75.4 µs, 2.44e-4).
// ---------------------------------------------------------------------------
__global__ __launch_bounds__(256, 2)
void attn_kernel(const u16* __restrict__ Qb, const u16* __restrict__ Kb,
                 const u16* __restrict__ Vb, u16* __restrict__ Op,
                 float* __restrict__ Lp)
{
    __shared__ __align__(16) u16 sK[2][KVB * 128];   // [buf][ktok][d], chunk c^(ktok&7)
    __shared__ __align__(16) u16 sV[2][128 * KVB];   // [buf][d][ktok], chunk c^(d&7)

    const int tid = threadIdx.x;
    const int lane = tid & 63, w = tid >> 6;        // 4 waves
    const int l31 = lane & 31, half = lane >> 5;

    // XCD-aware decode: b = lin&7 == XCD id.
    const int lin = blockIdx.x;
    const int b = lin & 7;
    const int r2 = lin >> 3;
    const int ks = r2 & 1;
    const int qt = r2 >> 1;                 // 0..31
    const int qbase = qt * 128 + w * 32;
    const int kbase = ks * (NTOK / KSPLIT);

    const u16* Kbat = Kb + (size_t)b * NTOK * DIM;
    const u16* Vbat = Vb + (size_t)b * DIM * NTOK;

    // 8 global_load_lds per wave per tile: 4 K-groups + 4 V-groups
#define STAGE(bufK, bufV, tt)                                                          \
    {                                                                                  \
        const u16* kb0 = Kbat + (size_t)(kbase + (tt) * KVB) * DIM;                    \
        _Pragma("unroll")                                                              \
        for (int i = 0; i < 4; ++i) {                                                  \
            const int row = w * 16 + i * 4 + (lane >> 4);                              \
            const int p = lane & 15;                                                   \
            const u16* g = kb0 + (size_t)row * DIM + ((p ^ (row & 7)) * 8);            \
            __builtin_amdgcn_global_load_lds(                                          \
                (const __attribute__((address_space(1))) unsigned int*)g,              \
                (__attribute__((address_space(3))) unsigned int*)&(bufK)[(w * 16 + i * 4) * 128], \
                16, 0, 0);                                                             \
        }                                                                              \
        const u16* vb0 = Vbat + kbase + (tt) * KVB;                                    \
        _Pragma("unroll")                                                              \
        for (int i = 0; i < 4; ++i) {                                                  \
            const int row = w * 32 + i * 8 + (lane >> 3);                              \
            const int p = lane & 7;                                                    \
            const u16* g = vb0 + (size_t)row * NTOK + ((p ^ (row & 7)) * 8);           \
            __builtin_amdgcn_global_load_lds(                                          \
                (const __attribute__((address_space(1))) unsigned int*)g,              \
                (__attribute__((address_space(3))) unsigned int*)&(bufV)[(w * 32 + i * 8) * 64], \
                16, 0, 0);                                                             \
        }                                                                              \
    }

    // Q fragments first (oldest vm-ops; counted waits stay conservative)
    short8 aQ[8];
    {
        const u16* qrow = Qb + ((size_t)b * NTOK + qbase + l31) * DIM + half * 8;
#pragma unroll
        for (int s = 0; s < 8; ++s) aQ[s] = *(const short8*)&qrow[s * 16];
    }

    STAGE(sK[0], sV[0], 0);
    STAGE(sK[1], sV[1], 1);

    f32x16 O[4];
#pragma unroll
    for (int i = 0; i < 4; ++i)
#pragma unroll
        for (int r = 0; r < 16; ++r) O[i][r] = 0.f;
    f32x16 SA0, SA1, SB0, SB1;
#pragma unroll
    for (int r = 0; r < 16; ++r) { SA0[r] = 0.f; SA1[r] = 0.f; }
    float lA = 0.f;

    // prologue: QK^T(0) into SA
    asm volatile("s_waitcnt vmcnt(8)" ::: "memory");   // stage0 done (stage1 in flight)
    __builtin_amdgcn_s_barrier();
    __builtin_amdgcn_sched_barrier(0);
    __builtin_amdgcn_s_setprio(1);
#pragma unroll
    for (int s = 0; s < 8; ++s) {
        const int pos = (((s * 2 + half) ^ (l31 & 7)) * 8);
        short8 k0 = *(const short8*)&sK[0][l31 * 128 + pos];
        short8 k1 = *(const short8*)&sK[0][(32 + l31) * 128 + pos];
        SA0 = __builtin_amdgcn_mfma_f32_32x32x16_bf16(k0, aQ[s], SA0, 0, 0, 0);
        SA1 = __builtin_amdgcn_mfma_f32_32x32x16_bf16(k1, aQ[s], SA1, 0, 0, 0);
    }
    __builtin_amdgcn_s_setprio(0);

    // softmax one k-group: 4 exp2 + lane-local l adds + 2 packed cvt
#define SM_ONE(s, SC0, SC1)                                                           \
    {                                                                                 \
        float p0 = __builtin_amdgcn_exp2f(((s) < 4 ? (SC0) : (SC1))[((s) & 3) * 4 + 0]); \
        float p1 = __builtin_amdgcn_exp2f(((s) < 4 ? (SC0) : (SC1))[((s) & 3) * 4 + 1]); \
        float p2 = __builtin_amdgcn_exp2f(((s) < 4 ? (SC0) : (SC1))[((s) & 3) * 4 + 2]); \
        float p3 = __builtin_amdgcn_exp2f(((s) < 4 ? (SC0) : (SC1))[((s) & 3) * 4 + 3]); \
        lA += (p0 + p1) + (p2 + p3);                                                  \
        asm("v_cvt_pk_bf16_f32 %0, %1, %2" : "=v"(xm[s]) : "v"(p0), "v"(p1));         \
        asm("v_cvt_pk_bf16_f32 %0, %1, %2" : "=v"(ym[s]) : "v"(p2), "v"(p3));         \
    }

    // one pipeline stage: softmax(SCur) interleaved with QK^T(t+1 -> SNext), PV(t)
#define BODY(t, SC0, SC1, SN0, SN1)                                                   \
    {                                                                                 \
        const bool hasNext = ((t) + 1 < KTILES);                                      \
        if (hasNext) {                                                                \
            asm volatile("s_waitcnt vmcnt(0)" ::: "memory");                          \
            __builtin_amdgcn_s_barrier();                                             \
            __builtin_amdgcn_sched_barrier(0);                                        \
        }                                                                             \
        const u16* sKn = &sK[((t) + 1) & 1][0];                                       \
        const u16* sVc = &sV[(t) & 1][0];                                             \
        unsigned xm[8], ym[8];                                                        \
        if (hasNext) {                                                                \
            _Pragma("unroll")                                                         \
            for (int r = 0; r < 16; ++r) { (SN0)[r] = 0.f; (SN1)[r] = 0.f; }          \
            __builtin_amdgcn_s_setprio(1);                                            \
            _Pragma("unroll")                                                         \
            for (int s = 0; s < 8; ++s) {                                             \
                const int pos = (((s * 2 + half) ^ (l31 & 7)) * 8);                   \
                short8 k0 = *(const short8*)&sKn[l31 * 128 + pos];                    \
                short8 k1 = *(const short8*)&sKn[(32 + l31) * 128 + pos];             \
                (SN0) = __builtin_amdgcn_mfma_f32_32x32x16_bf16(k0, aQ[s], (SN0), 0, 0, 0); \
                (SN1) = __builtin_amdgcn_mfma_f32_32x32x16_bf16(k1, aQ[s], (SN1), 0, 0, 0); \
                SM_ONE(s, SC0, SC1)                                                   \
            }                                                                         \
            __builtin_amdgcn_s_setprio(0);                                            \
        } else {                                                                      \
            _Pragma("unroll")                                                         \
            for (int s = 0; s < 8; ++s) SM_ONE(s, SC0, SC1)                           \
        }                                                                             \
        short8 pa[4];                                                                 \
        _Pragma("unroll")                                                             \
        for (int s2 = 0; s2 < 4; ++s2) {                                              \
            unsigned xa = xm[2 * s2], xb = xm[2 * s2 + 1];                            \
            unsigned ya = ym[2 * s2], yb = ym[2 * s2 + 1];                            \
            asm("v_permlane32_swap_b32 %0, %1" : "+v"(xa), "+v"(xb));                 \
            asm("v_permlane32_swap_b32 %0, %1" : "+v"(ya), "+v"(yb));                 \
            pa[s2] = mk8(xa, ya, xb, yb);                                             \
        }                                                                             \
        __builtin_amdgcn_s_setprio(1);                                                \
        _Pragma("unroll")                                                             \
        for (int dblk = 0; dblk < 4; ++dblk) {                                        \
            const int vrow = dblk * 32 + l31;                                         \
            _Pragma("unroll")                                                         \
            for (int s2 = 0; s2 < 4; ++s2) {                                          \
                short8 v = *(const short8*)&sVc[vrow * 64 + (((s2 * 2 + half) ^ (l31 & 7)) * 8)]; \
                O[dblk] = __builtin_amdgcn_mfma_f32_32x32x16_bf16(pa[s2], v, O[dblk], 0, 0, 0); \
            }                                                                         \
        }                                                                             \
        __builtin_amdgcn_s_setprio(0);                                                \
        __builtin_amdgcn_sched_barrier(0);                                            \
        __builtin_amdgcn_s_barrier();                                                 \
        __builtin_amdgcn_sched_barrier(0);                                            \
        if ((t) + 2 < KTILES) STAGE(sK[(t) & 1], sV[(t) & 1], (t) + 2);               \
    }

#pragma unroll 1
    for (int tp = 0; tp < KTILES; tp += 2) {
        BODY(tp,     SA0, SA1, SB0, SB1)
        BODY(tp + 1, SB0, SB1, SA0, SA1)
    }
#undef BODY
#undef SM_ONE
#undef STAGE

    // ---- epilogue: store UNNORMALIZED partials
    float lt = lA + __shfl_xor(lA, 32, 64);
    if (half == 0) {
        float* lp = Lp + (size_t)(ks * BATCH + b) * NTOK + qbase;
        lp[l31] = lt;
    }

    u16* obase = Op + ((size_t)(ks * BATCH + b) * NTOK + qbase) * DIM;
#pragma unroll
    for (int dblk = 0; dblk < 4; ++dblk)
#pragma unroll
        for (int r = 0; r < 16; ++r) {
            const int q = (r & 3) + 8 * (r >> 2) + 4 * half;
            obase[(size_t)q * DIM + dblk * 32 + l31] = f2bf(O[dblk][r]);
        }
}

// ---------------------------------------------------------------------------
// Kernel 3: combine split-K partials + MFMA output projection (round 13).
// ---------------------------------------------------------------------------
__global__ __launch_bounds__(256)
void oproj_kernel(const u16* __restrict__ Op, const float* __restrict__ Lp,
                  const u16* __restrict__ Wob, const float* __restrict__ bo,
                  float* __restrict__ Out)
{
    __shared__ __align__(16) u16 sA[64 * 128];   // [n][d], 16B chunk at c^(n&7)

    const int tid = threadIdx.x, lane = tid & 63, w = tid >> 6;
    const int l31 = lane & 31, half = lane >> 5;
    const int b = blockIdx.y;
    const int nbase = blockIdx.x * 64;

    // ---- combine split-K partials, normalize, stage bf16 to swizzled LDS
#pragma unroll
    for (int i = 0; i < 4; ++i) {
        int idx = tid + 256 * i;
        int c = idx & 15, n = idx >> 4;
        const size_t r0 = ((size_t)b * NTOK + nbase + n) * DIM + c * 8;
        const size_t r1 = ((size_t)(BATCH + b) * NTOK + nbase + n) * DIM + c * 8;
        uint4 v0 = *(const uint4*)&Op[r0];
        uint4 v1 = *(const uint4*)&Op[r1];
        float l = Lp[(size_t)b * NTOK + nbase + n] +
                  Lp[(size_t)(BATCH + b) * NTOK + nbase + n];
        float inv = 1.f / l;
        unsigned t0[4] = {v0.x, v0.y, v0.z, v0.w};
        unsigned t1[4] = {v1.x, v1.y, v1.z, v1.w};
        short8 o;
#pragma unroll
        for (int j = 0; j < 8; ++j) {
            float a  = bf2f((u16)(t0[j >> 1] >> ((j & 1) * 16)));
            float a2 = bf2f((u16)(t1[j >> 1] >> ((j & 1) * 16)));
            o[j] = (short)f2bf((a + a2) * inv);
        }
        *(short8*)&sA[n * 128 + ((c ^ (n & 7)) * 8)] = o;
    }
    __syncthreads();

    // ---- MFMA: acc[nsub] += A(sA rows) x B(Wo rows)
    const int co = w * 32 + l31;
    const u16* wr = Wob + (size_t)co * DIM + half * 8;
    f32x16 acc0, acc1;
#pragma unroll
    for (int r = 0; r < 16; ++r) { acc0[r] = 0.f; acc1[r] = 0.f; }
#pragma unroll
    for (int kc = 0; kc < 8; ++kc) {
        const int ch = kc * 2 + half;
        short8 a0 = *(const short8*)&sA[l31 * 128 + ((ch ^ (l31 & 7)) * 8)];
        short8 a1 = *(const short8*)&sA[(32 + l31) * 128 + ((ch ^ (l31 & 7)) * 8)];
        short8 bw = *(const short8*)(wr + kc * 16);
        acc0 = __builtin_amdgcn_mfma_f32_32x32x16_bf16(a0, bw, acc0, 0, 0, 0);
        acc1 = __builtin_amdgcn_mfma_f32_32x32x16_bf16(a1, bw, acc1, 0, 0, 0);
    }

    // ---- epilogue: Out[b][co][nbase + n] = acc + bo[co]
    const float bb = bo[co];
    float* ob = Out + ((size_t)b * DIM + co) * NTOK + nbase;
#pragma unroll
    for (int r = 0; r < 16; ++r) {
        const int n = (r & 3) + 8 * (r >> 2) + 4 * half;
        ob[n] = acc0[r] + bb;
        ob[n + 32] = acc1[r] + bb;
    }
}

// ---------------------------------------------------------------------------
extern "C" void kernel_launch(void* const* d_in, const int* in_sizes, int n_in,
                              void* d_out, int out_size, void* d_ws, size_t ws_size,
                              hipStream_t stream)
{
    const float* cape = (const float*)d_in[0];
    const float* era5 = (const float*)d_in[1];
    const float* Wq = (const float*)d_in[2];
    const float* bq = (const float*)d_in[3];
    const float* Wk = (const float*)d_in[4];
    const float* bk = (const float*)d_in[5];
    const float* Wv = (const float*)d_in[6];
    const float* bv = (const float*)d_in[7];
    const float* Wo = (const float*)d_in[8];
    const float* bo = (const float*)d_in[9];

    const size_t QKV = (size_t)BATCH * NTOK * DIM;
    u16* Qb  = (u16*)d_ws;
    u16* Kb  = Qb + QKV;
    u16* Vb  = Kb + QKV;
    u16* Wqb = Vb + QKV;
    u16* Wkb = Wqb + 16384;
    u16* Wvb = Wkb + 32768;
    u16* Wob = Wvb + 32768;
    u16* Op  = Wob + 16384;
    float* Lp = (float*)(Op + (size_t)KSPLIT * QKV);

    hipLaunchKernelGGL(wconv_kernel, dim3(96), dim3(256), 0, stream,
                       Wq, Wk, Wv, Wo, Wqb, Wkb, Wvb, Wob);
    hipLaunchKernelGGL(qkv_fused_kernel, dim3(64, BATCH), dim3(256), 0, stream,
                       cape, era5, Wqb, Wkb, Wvb, bq, bk, bv, Qb, Kb, Vb);
    hipLaunchKernelGGL(attn_kernel, dim3((NTOK / 128) * KSPLIT * BATCH), dim3(256), 0, stream,
                       Qb, Kb, Vb, Op, Lp);
    hipLaunchKernelGGL(oproj_kernel, dim3(64, BATCH), dim3(256), 0, stream,
                       Op, Lp, Wob, bo, (float*)d_out);
}

// Round 18
// 106.658 us; speedup vs baseline: 1.6081x; 1.0165x over previous
//
#include <hip/hip_runtime.h>

typedef unsigned short u16;
typedef __attribute__((ext_vector_type(8))) short short8;
typedef __attribute__((ext_vector_type(4))) float f32x4;
typedef __attribute__((ext_vector_type(16))) float f32x16;

constexpr int BATCH = 8, CC = 128, CE = 256, DIM = 128, NTOK = 4096;
constexpr int KSPLIT = 2, KVB = 64, KTILES = NTOK / KSPLIT / KVB;   // 32 tiles
// 1/sqrt(128) * log2(e), folded into Wq/bq at conversion time
constexpr float KSC = 0.088388347648318447f * 1.4426950408889634f;

#define DEV static __device__ __forceinline__

DEV u16 f2bf(float f) {
    union { float f; unsigned u; } v; v.f = f;
    unsigned r = (v.u + 0x7fffu + ((v.u >> 16) & 1u)) >> 16;
    return (u16)r;
}
DEV float bf2f(u16 h) {
    union { unsigned u; float f; } v; v.u = ((unsigned)h) << 16;
    return v.f;
}
DEV short8 mk8(unsigned a, unsigned b, unsigned c, unsigned d) {
    union { unsigned u[4]; short8 s; } t; t.u[0] = a; t.u[1] = b; t.u[2] = c; t.u[3] = d;
    return t.s;
}

// ---------------------------------------------------------------------------
// Kernel 0: convert Wq/Wk/Wv/Wo f32 -> bf16. Wq pre-scaled by KSC. grid 96.
// ---------------------------------------------------------------------------
__global__ __launch_bounds__(256)
void wconv_kernel(const float* __restrict__ Wq, const float* __restrict__ Wk,
                  const float* __restrict__ Wv, const float* __restrict__ Wo,
                  u16* __restrict__ Wqb, u16* __restrict__ Wkb,
                  u16* __restrict__ Wvb, u16* __restrict__ Wob)
{
    int lin = (blockIdx.x * 256 + threadIdx.x) * 4;
    const float* s; u16* d; int off; float sc;
    if (lin < 16384)      { s = Wq; d = Wqb; off = lin; sc = KSC; }
    else if (lin < 49152) { s = Wk; d = Wkb; off = lin - 16384; sc = 1.f; }
    else if (lin < 81920) { s = Wv; d = Wvb; off = lin - 49152; sc = 1.f; }
    else                  { s = Wo; d = Wob; off = lin - 81920; sc = 1.f; }
    float4 v = *(const float4*)&s[off];
    ushort4 h; h.x = f2bf(v.x * sc); h.y = f2bf(v.y * sc);
    h.z = f2bf(v.z * sc); h.w = f2bf(v.w * sc);
    *(ushort4*)&d[off] = h;
}

// ---------------------------------------------------------------------------
// Kernel 1: FUSED transpose + MFMA QKV projection, T14 register-prefetch:
// chunk (e+1)'s global loads (PF -> regs) are issued under chunk e's compute;
// convert+LDS-write (WR) lands after the barrier. Same addresses, same math,
// same barrier count as round 17 — only load-issue timing moves.
// ---------------------------------------------------------------------------
__global__ __launch_bounds__(256)
void qkv_fused_kernel(const float* __restrict__ cape, const float* __restrict__ era5,
                      const u16* __restrict__ Wqb, const u16* __restrict__ Wkb,
                      const u16* __restrict__ Wvb, const float* __restrict__ bq,
                      const float* __restrict__ bk, const float* __restrict__ bv,
                      u16* __restrict__ Qb, u16* __restrict__ Kb, u16* __restrict__ Vb)
{
    __shared__ __align__(16) u16 sX[64 * 68];      // [c 64][n 64] pitch 68
    __shared__ __align__(16) u16 sT[4][32 * 68];   // per-wave V transpose tile

    const int tid = threadIdx.x, lane = tid & 63, w = tid >> 6;
    const int l31 = lane & 31, half = lane >> 5;
    const int b = blockIdx.y, nbase = blockIdx.x * 64;
    const int d = w * 32 + l31;

    const float* capeB = cape + (size_t)b * CC * NTOK + nbase;
    const float* era5B = era5 + (size_t)b * CE * NTOK + nbase;

    const int sc_ = tid >> 4, sn4 = (tid & 15) * 4;   // stage coords: rows sc_+16i
    float4 pf[4];

    // PF: issue chunk's 4 global float4 loads into registers
#define PF(srcbase)                                                           \
    { _Pragma("unroll")                                                       \
      for (int i = 0; i < 4; ++i)                                             \
          pf[i] = *(const float4*)&(srcbase)[(size_t)(sc_ + 16 * i) * NTOK + sn4]; }
    // WR: convert + write staged registers to pitch-68 LDS
#define WR()                                                                  \
    { _Pragma("unroll")                                                       \
      for (int i = 0; i < 4; ++i) {                                           \
          ushort4 h; h.x = f2bf(pf[i].x); h.y = f2bf(pf[i].y);                \
          h.z = f2bf(pf[i].z); h.w = f2bf(pf[i].w);                           \
          *(ushort4*)&sX[(sc_ + 16 * i) * 68 + sn4] = h; } }
    // gather A-frags (rows l31 and 32+l31; c = kcl*16 + half*8 + j)
#define GATHER(kcl, a0, a1)                                                   \
    {                                                                         \
        _Pragma("unroll")                                                     \
        for (int j = 0; j < 8; ++j) {                                         \
            int c = (kcl) * 16 + half * 8 + j;                                \
            (a0)[j] = (short)sX[c * 68 + l31];                                \
            (a1)[j] = (short)sX[c * 68 + 32 + l31];                           \
        }                                                                     \
    }

    // ---- Q: cape, 2 chunks of 64 c
    f32x16 aq0, aq1;
#pragma unroll
    for (int r = 0; r < 16; ++r) { aq0[r] = 0.f; aq1[r] = 0.f; }
    const u16* wq = Wqb + (size_t)d * CC + half * 8;

    PF(capeB);                                  // cape chunk 0
    WR();
    PF(capeB + (size_t)64 * NTOK);              // cape chunk 1 in flight
    __syncthreads();
#pragma unroll
    for (int kcl = 0; kcl < 4; ++kcl) {         // compute cape chunk 0
        short8 a0, a1;
        GATHER(kcl, a0, a1);
        short8 bw = *(const short8*)(wq + kcl * 16);
        aq0 = __builtin_amdgcn_mfma_f32_32x32x16_bf16(a0, bw, aq0, 0, 0, 0);
        aq1 = __builtin_amdgcn_mfma_f32_32x32x16_bf16(a1, bw, aq1, 0, 0, 0);
    }
    __syncthreads();
    WR();                                       // cape chunk 1 -> LDS
    PF(era5B);                                  // era5 chunk 0 in flight
    __syncthreads();
#pragma unroll
    for (int kcl = 0; kcl < 4; ++kcl) {         // compute cape chunk 1
        short8 a0, a1;
        GATHER(kcl, a0, a1);
        short8 bw = *(const short8*)(wq + (4 + kcl) * 16);
        aq0 = __builtin_amdgcn_mfma_f32_32x32x16_bf16(a0, bw, aq0, 0, 0, 0);
        aq1 = __builtin_amdgcn_mfma_f32_32x32x16_bf16(a1, bw, aq1, 0, 0, 0);
    }
    {
        const float bias = bq[d] * KSC;
        u16* q0 = Qb + ((size_t)b * NTOK + nbase) * DIM + d;
#pragma unroll
        for (int r = 0; r < 16; ++r) {
            const int nl = (r & 3) + 8 * (r >> 2) + 4 * half;
            q0[(size_t)nl * DIM] = f2bf(aq0[r] + bias);
            q0[(size_t)(nl + 32) * DIM] = f2bf(aq1[r] + bias);
        }
    }

    // ---- K & V: era5, 4 chunks of 64 c, shared A-frags
    f32x16 ak0, ak1, av0, av1;
#pragma unroll
    for (int r = 0; r < 16; ++r) { ak0[r] = 0.f; ak1[r] = 0.f; av0[r] = 0.f; av1[r] = 0.f; }
    const u16* wk = Wkb + (size_t)d * CE + half * 8;
    const u16* wv = Wvb + (size_t)d * CE + half * 8;
#pragma unroll 1
    for (int e = 0; e < 4; ++e) {
        __syncthreads();
        WR();                                   // era5 chunk e -> LDS
        if (e < 3) PF(era5B + (size_t)((e + 1) * 64) * NTOK);   // e+1 in flight
        __syncthreads();
#pragma unroll
        for (int kcl = 0; kcl < 4; ++kcl) {
            short8 a0, a1;
            GATHER(kcl, a0, a1);
            short8 bwk = *(const short8*)(wk + (e * 4 + kcl) * 16);
            short8 bwv = *(const short8*)(wv + (e * 4 + kcl) * 16);
            ak0 = __builtin_amdgcn_mfma_f32_32x32x16_bf16(a0, bwk, ak0, 0, 0, 0);
            ak1 = __builtin_amdgcn_mfma_f32_32x32x16_bf16(a1, bwk, ak1, 0, 0, 0);
            av0 = __builtin_amdgcn_mfma_f32_32x32x16_bf16(a0, bwv, av0, 0, 0, 0);
            av1 = __builtin_amdgcn_mfma_f32_32x32x16_bf16(a1, bwv, av1, 0, 0, 0);
        }
    }
    {
        const float bias = bk[d];
        u16* k0 = Kb + ((size_t)b * NTOK + nbase) * DIM + d;
#pragma unroll
        for (int r = 0; r < 16; ++r) {
            const int nl = (r & 3) + 8 * (r >> 2) + 4 * half;
            k0[(size_t)nl * DIM] = f2bf(ak0[r] + bias);
            k0[(size_t)(nl + 32) * DIM] = f2bf(ak1[r] + bias);
        }
    }
    // V: frag rows = n, cols = d -> transpose via per-wave LDS (pitch 68)
    {
        const float bias = bv[d];
        u16* t = &sT[w][0];
#pragma unroll
        for (int r = 0; r < 16; ++r) {
            const int nl = (r & 3) + 8 * (r >> 2) + 4 * half;
            t[l31 * 68 + nl] = f2bf(av0[r] + bias);
            t[l31 * 68 + nl + 32] = f2bf(av1[r] + bias);
        }
#pragma unroll
        for (int i = 0; i < 4; ++i) {
            int rlin = lane + 64 * i;
            int dl = rlin >> 3, n8 = (rlin & 7) * 8;
            uint2 p0 = *(const uint2*)&t[dl * 68 + n8];
            uint2 p1 = *(const uint2*)&t[dl * 68 + n8 + 4];
            uint4 o = {p0.x, p0.y, p1.x, p1.y};
            *(uint4*)&Vb[((size_t)b * DIM + w * 32 + dl) * NTOK + nbase + n8] = o;
        }
    }
#undef PF
#undef WR
#undef GATHER
}

// ---------------------------------------------------------------------------
// Kernel 2: flash attention — EXACT round-13 kernel (proven 75.4 µs, 2.44e-4).
// ---------------------------------------------------------------------------
__global__ __launch_bounds__(256, 2)
void attn_kernel(const u16* __restrict__ Qb, const u16* __restrict__ Kb,
                 const u16* __restrict__ Vb, u16* __restrict__ Op,
                 float* __restrict__ Lp)
{
    __shared__ __align__(16) u16 sK[2][KVB * 128];   // [buf][ktok][d], chunk c^(ktok&7)
    __shared__ __align__(16) u16 sV[2][128 * KVB];   // [buf][d][ktok], chunk c^(d&7)

    const int tid = threadIdx.x;
    const int lane = tid & 63, w = tid >> 6;        // 4 waves
    const int l31 = lane & 31, half = lane >> 5;

    // XCD-aware decode: b = lin&7 == XCD id.
    const int lin = blockIdx.x;
    const int b = lin & 7;
    const int r2 = lin >> 3;
    const int ks = r2 & 1;
    const int qt = r2 >> 1;                 // 0..31
    const int qbase = qt * 128 + w * 32;
    const int kbase = ks * (NTOK / KSPLIT);

    const u16* Kbat = Kb + (size_t)b * NTOK * DIM;
    const u16* Vbat = Vb + (size_t)b * DIM * NTOK;

    // 8 global_load_lds per wave per tile: 4 K-groups + 4 V-groups
#define STAGE(bufK, bufV, tt)                                                          \
    {                                                                                  \
        const u16* kb0 = Kbat + (size_t)(kbase + (tt) * KVB) * DIM;                    \
        _Pragma("unroll")                                                              \
        for (int i = 0; i < 4; ++i) {                                                  \
            const int row = w * 16 + i * 4 + (lane >> 4);                              \
            const int p = lane & 15;                                                   \
            const u16* g = kb0 + (size_t)row * DIM + ((p ^ (row & 7)) * 8);            \
            __builtin_amdgcn_global_load_lds(                                          \
                (const __attribute__((address_space(1))) unsigned int*)g,              \
                (__attribute__((address_space(3))) unsigned int*)&(bufK)[(w * 16 + i * 4) * 128], \
                16, 0, 0);                                                             \
        }                                                                              \
        const u16* vb0 = Vbat + kbase + (tt) * KVB;                                    \
        _Pragma("unroll")                                                              \
        for (int i = 0; i < 4; ++i) {                                                  \
            const int row = w * 32 + i * 8 + (lane >> 3);                              \
            const int p = lane & 7;                                                    \
            const u16* g = vb0 + (size_t)row * NTOK + ((p ^ (row & 7)) * 8);           \
            __builtin_amdgcn_global_load_lds(                                          \
                (const __attribute__((address_space(1))) unsigned int*)g,              \
                (__attribute__((address_space(3))) unsigned int*)&(bufV)[(w * 32 + i * 8) * 64], \
                16, 0, 0);                                                             \
        }                                                                              \
    }

    // Q fragments first (oldest vm-ops; counted waits stay conservative)
    short8 aQ[8];
    {
        const u16* qrow = Qb + ((size_t)b * NTOK + qbase + l31) * DIM + half * 8;
#pragma unroll
        for (int s = 0; s < 8; ++s) aQ[s] = *(const short8*)&qrow[s * 16];
    }

    STAGE(sK[0], sV[0], 0);
    STAGE(sK[1], sV[1], 1);

    f32x16 O[4];
#pragma unroll
    for (int i = 0; i < 4; ++i)
#pragma unroll
        for (int r = 0; r < 16; ++r) O[i][r] = 0.f;
    f32x16 SA0, SA1, SB0, SB1;
#pragma unroll
    for (int r = 0; r < 16; ++r) { SA0[r] = 0.f; SA1[r] = 0.f; }
    float lA = 0.f;

    // prologue: QK^T(0) into SA
    asm volatile("s_waitcnt vmcnt(8)" ::: "memory");   // stage0 done (stage1 in flight)
    __builtin_amdgcn_s_barrier();
    __builtin_amdgcn_sched_barrier(0);
    __builtin_amdgcn_s_setprio(1);
#pragma unroll
    for (int s = 0; s < 8; ++s) {
        const int pos = (((s * 2 + half) ^ (l31 & 7)) * 8);
        short8 k0 = *(const short8*)&sK[0][l31 * 128 + pos];
        short8 k1 = *(const short8*)&sK[0][(32 + l31) * 128 + pos];
        SA0 = __builtin_amdgcn_mfma_f32_32x32x16_bf16(k0, aQ[s], SA0, 0, 0, 0);
        SA1 = __builtin_amdgcn_mfma_f32_32x32x16_bf16(k1, aQ[s], SA1, 0, 0, 0);
    }
    __builtin_amdgcn_s_setprio(0);

    // softmax one k-group: 4 exp2 + lane-local l adds + 2 packed cvt
#define SM_ONE(s, SC0, SC1)                                                           \
    {                                                                                 \
        float p0 = __builtin_amdgcn_exp2f(((s) < 4 ? (SC0) : (SC1))[((s) & 3) * 4 + 0]); \
        float p1 = __builtin_amdgcn_exp2f(((s) < 4 ? (SC0) : (SC1))[((s) & 3) * 4 + 1]); \
        float p2 = __builtin_amdgcn_exp2f(((s) < 4 ? (SC0) : (SC1))[((s) & 3) * 4 + 2]); \
        float p3 = __builtin_amdgcn_exp2f(((s) < 4 ? (SC0) : (SC1))[((s) & 3) * 4 + 3]); \
        lA += (p0 + p1) + (p2 + p3);                                                  \
        asm("v_cvt_pk_bf16_f32 %0, %1, %2" : "=v"(xm[s]) : "v"(p0), "v"(p1));         \
        asm("v_cvt_pk_bf16_f32 %0, %1, %2" : "=v"(ym[s]) : "v"(p2), "v"(p3));         \
    }

    // one pipeline stage: softmax(SCur) interleaved with QK^T(t+1 -> SNext), PV(t)
#define BODY(t, SC0, SC1, SN0, SN1)                                                   \
    {                                                                                 \
        const bool hasNext = ((t) + 1 < KTILES);                                      \
        if (hasNext) {                                                                \
            asm volatile("s_waitcnt vmcnt(0)" ::: "memory");                          \
            __builtin_amdgcn_s_barrier();                                             \
            __builtin_amdgcn_sched_barrier(0);                                        \
        }                                                                             \
        const u16* sKn = &sK[((t) + 1) & 1][0];                                       \
        const u16* sVc = &sV[(t) & 1][0];                                             \
        unsigned xm[8], ym[8];                                                        \
        if (hasNext) {                                                                \
            _Pragma("unroll")                                                         \
            for (int r = 0; r < 16; ++r) { (SN0)[r] = 0.f; (SN1)[r] = 0.f; }          \
            __builtin_amdgcn_s_setprio(1);                                            \
            _Pragma("unroll")                                                         \
            for (int s = 0; s < 8; ++s) {                                             \
                const int pos = (((s * 2 + half) ^ (l31 & 7)) * 8);                   \
                short8 k0 = *(const short8*)&sKn[l31 * 128 + pos];                    \
                short8 k1 = *(const short8*)&sKn[(32 + l31) * 128 + pos];             \
                (SN0) = __builtin_amdgcn_mfma_f32_32x32x16_bf16(k0, aQ[s], (SN0), 0, 0, 0); \
                (SN1) = __builtin_amdgcn_mfma_f32_32x32x16_bf16(k1, aQ[s], (SN1), 0, 0, 0); \
                SM_ONE(s, SC0, SC1)                                                   \
            }                                                                         \
            __builtin_amdgcn_s_setprio(0);                                            \
        } else {                                                                      \
            _Pragma("unroll")                                                         \
            for (int s = 0; s < 8; ++s) SM_ONE(s, SC0, SC1)                           \
        }                                                                             \
        short8 pa[4];                                                                 \
        _Pragma("unroll")                                                             \
        for (int s2 = 0; s2 < 4; ++s2) {                                              \
            unsigned xa = xm[2 * s2], xb = xm[2 * s2 + 1];                            \
            unsigned ya = ym[2 * s2], yb = ym[2 * s2 + 1];                            \
            asm("v_permlane32_swap_b32 %0, %1" : "+v"(xa), "+v"(xb));                 \
            asm("v_permlane32_swap_b32 %0, %1" : "+v"(ya), "+v"(yb));                 \
            pa[s2] = mk8(xa, ya, xb, yb);                                             \
        }                                                                             \
        __builtin_amdgcn_s_setprio(1);                                                \
        _Pragma("unroll")                                                             \
        for (int dblk = 0; dblk < 4; ++dblk) {                                        \
            const int vrow = dblk * 32 + l31;                                         \
            _Pragma("unroll")                                                         \
            for (int s2 = 0; s2 < 4; ++s2) {                                          \
                short8 v = *(const short8*)&sVc[vrow * 64 + (((s2 * 2 + half) ^ (l31 & 7)) * 8)]; \
                O[dblk] = __builtin_amdgcn_mfma_f32_32x32x16_bf16(pa[s2], v, O[dblk], 0, 0, 0); \
            }                                                                         \
        }                                                                             \
        __builtin_amdgcn_s_setprio(0);                                                \
        __builtin_amdgcn_sched_barrier(0);                                            \
        __builtin_amdgcn_s_barrier();                                                 \
        __builtin_amdgcn_sched_barrier(0);                                            \
        if ((t) + 2 < KTILES) STAGE(sK[(t) & 1], sV[(t) & 1], (t) + 2);               \
    }

#pragma unroll 1
    for (int tp = 0; tp < KTILES; tp += 2) {
        BODY(tp,     SA0, SA1, SB0, SB1)
        BODY(tp + 1, SB0, SB1, SA0, SA1)
    }
#undef BODY
#undef SM_ONE
#undef STAGE

    // ---- epilogue: store UNNORMALIZED partials
    float lt = lA + __shfl_xor(lA, 32, 64);
    if (half == 0) {
        float* lp = Lp + (size_t)(ks * BATCH + b) * NTOK + qbase;
        lp[l31] = lt;
    }

    u16* obase = Op + ((size_t)(ks * BATCH + b) * NTOK + qbase) * DIM;
#pragma unroll
    for (int dblk = 0; dblk < 4; ++dblk)
#pragma unroll
        for (int r = 0; r < 16; ++r) {
            const int q = (r & 3) + 8 * (r >> 2) + 4 * half;
            obase[(size_t)q * DIM + dblk * 32 + l31] = f2bf(O[dblk][r]);
        }
}

// ---------------------------------------------------------------------------
// Kernel 3: combine split-K partials + MFMA output projection (round 13).
// ---------------------------------------------------------------------------
__global__ __launch_bounds__(256)
void oproj_kernel(const u16* __restrict__ Op, const float* __restrict__ Lp,
                  const u16* __restrict__ Wob, const float* __restrict__ bo,
                  float* __restrict__ Out)
{
    __shared__ __align__(16) u16 sA[64 * 128];   // [n][d], 16B chunk at c^(n&7)

    const int tid = threadIdx.x, lane = tid & 63, w = tid >> 6;
    const int l31 = lane & 31, half = lane >> 5;
    const int b = blockIdx.y;
    const int nbase = blockIdx.x * 64;

    // ---- combine split-K partials, normalize, stage bf16 to swizzled LDS
#pragma unroll
    for (int i = 0; i < 4; ++i) {
        int idx = tid + 256 * i;
        int c = idx & 15, n = idx >> 4;
        const size_t r0 = ((size_t)b * NTOK + nbase + n) * DIM + c * 8;
        const size_t r1 = ((size_t)(BATCH + b) * NTOK + nbase + n) * DIM + c * 8;
        uint4 v0 = *(const uint4*)&Op[r0];
        uint4 v1 = *(const uint4*)&Op[r1];
        float l = Lp[(size_t)b * NTOK + nbase + n] +
                  Lp[(size_t)(BATCH + b) * NTOK + nbase + n];
        float inv = 1.f / l;
        unsigned t0[4] = {v0.x, v0.y, v0.z, v0.w};
        unsigned t1[4] = {v1.x, v1.y, v1.z, v1.w};
        short8 o;
#pragma unroll
        for (int j = 0; j < 8; ++j) {
            float a  = bf2f((u16)(t0[j >> 1] >> ((j & 1) * 16)));
            float a2 = bf2f((u16)(t1[j >> 1] >> ((j & 1) * 16)));
            o[j] = (short)f2bf((a + a2) * inv);
        }
        *(short8*)&sA[n * 128 + ((c ^ (n & 7)) * 8)] = o;
    }
    __syncthreads();

    // ---- MFMA: acc[nsub] += A(sA rows) x B(Wo rows)
    const int co = w * 32 + l31;
    const u16* wr = Wob + (size_t)co * DIM + half * 8;
    f32x16 acc0, acc1;
#pragma unroll
    for (int r = 0; r < 16; ++r) { acc0[r] = 0.f; acc1[r] = 0.f; }
#pragma unroll
    for (int kc = 0; kc < 8; ++kc) {
        const int ch = kc * 2 + half;
        short8 a0 = *(const short8*)&sA[l31 * 128 + ((ch ^ (l31 & 7)) * 8)];
        short8 a1 = *(const short8*)&sA[(32 + l31) * 128 + ((ch ^ (l31 & 7)) * 8)];
        short8 bw = *(const short8*)(wr + kc * 16);
        acc0 = __builtin_amdgcn_mfma_f32_32x32x16_bf16(a0, bw, acc0, 0, 0, 0);
        acc1 = __builtin_amdgcn_mfma_f32_32x32x16_bf16(a1, bw, acc1, 0, 0, 0);
    }

    // ---- epilogue: Out[b][co][nbase + n] = acc + bo[co]
    const float bb = bo[co];
    float* ob = Out + ((size_t)b * DIM + co) * NTOK + nbase;
#pragma unroll
    for (int r = 0; r < 16; ++r) {
        const int n = (r & 3) + 8 * (r >> 2) + 4 * half;
        ob[n] = acc0[r] + bb;
        ob[n + 32] = acc1[r] + bb;
    }
}

// ---------------------------------------------------------------------------
extern "C" void kernel_launch(void* const* d_in, const int* in_sizes, int n_in,
                              void* d_out, int out_size, void* d_ws, size_t ws_size,
                              hipStream_t stream)
{
    const float* cape = (const float*)d_in[0];
    const float* era5 = (const float*)d_in[1];
    const float* Wq = (const float*)d_in[2];
    const float* bq = (const float*)d_in[3];
    const float* Wk = (const float*)d_in[4];
    const float* bk = (const float*)d_in[5];
    const float* Wv = (const float*)d_in[6];
    const float* bv = (const float*)d_in[7];
    const float* Wo = (const float*)d_in[8];
    const float* bo = (const float*)d_in[9];

    const size_t QKV = (size_t)BATCH * NTOK * DIM;
    u16* Qb  = (u16*)d_ws;
    u16* Kb  = Qb + QKV;
    u16* Vb  = Kb + QKV;
    u16* Wqb = Vb + QKV;
    u16* Wkb = Wqb + 16384;
    u16* Wvb = Wkb + 32768;
    u16* Wob = Wvb + 32768;
    u16* Op  = Wob + 16384;
    float* Lp = (float*)(Op + (size_t)KSPLIT * QKV);

    hipLaunchKernelGGL(wconv_kernel, dim3(96), dim3(256), 0, stream,
                       Wq, Wk, Wv, Wo, Wqb, Wkb, Wvb, Wob);
    hipLaunchKernelGGL(qkv_fused_kernel, dim3(64, BATCH), dim3(256), 0, stream,
                       cape, era5, Wqb, Wkb, Wvb, bq, bk, bv, Qb, Kb, Vb);
    hipLaunchKernelGGL(attn_kernel, dim3((NTOK / 128) * KSPLIT * BATCH), dim3(256), 0, stream,
                       Qb, Kb, Vb, Op, Lp);
    hipLaunchKernelGGL(oproj_kernel, dim3(64, BATCH), dim3(256), 0, stream,
                       Op, Lp, Wob, bo, (float*)d_out);
}